// Round 1
// baseline (142.479 us; speedup 1.0000x reference)
//
#include <hip/hip_runtime.h>

// Key insight: coords are all in {0,1}, and STRIDES is a mixed-radix positional
// encoding (strictly decreasing, each stride > sum of all smaller contributions
// for 0/1 coords). So row -> 16-bit pattern (bit d = coord[d]) is a bijection
// onto the reachable key set. The whole op is a 65536-bin float histogram
// (scatter-add) followed by a gather.

#define NBINS 65536
#define REL_W 16

__global__ void build_hist_kernel(const int* __restrict__ coords,
                                  const float* __restrict__ vals,
                                  float* __restrict__ hist, int n) {
    int i = blockIdx.x * blockDim.x + threadIdx.x;
    if (i >= n) return;
    const int4* p = reinterpret_cast<const int4*>(coords + (size_t)i * REL_W);
    unsigned pat = 0;
#pragma unroll
    for (int k = 0; k < 4; ++k) {
        int4 v = p[k];
        pat |= (unsigned)(v.x & 1) << (k * 4 + 0);
        pat |= (unsigned)(v.y & 1) << (k * 4 + 1);
        pat |= (unsigned)(v.z & 1) << (k * 4 + 2);
        pat |= (unsigned)(v.w & 1) << (k * 4 + 3);
    }
    atomicAdd(&hist[pat], vals[i]);
}

__global__ void gather_kernel(const int* __restrict__ queries,
                              const float* __restrict__ hist,
                              float* __restrict__ out, int n) {
    int i = blockIdx.x * blockDim.x + threadIdx.x;
    if (i >= n) return;
    const int4* p = reinterpret_cast<const int4*>(queries + (size_t)i * REL_W);
    unsigned pat = 0;
#pragma unroll
    for (int k = 0; k < 4; ++k) {
        int4 v = p[k];
        pat |= (unsigned)(v.x & 1) << (k * 4 + 0);
        pat |= (unsigned)(v.y & 1) << (k * 4 + 1);
        pat |= (unsigned)(v.z & 1) << (k * 4 + 2);
        pat |= (unsigned)(v.w & 1) << (k * 4 + 3);
    }
    out[i] = hist[pat];
}

extern "C" void kernel_launch(void* const* d_in, const int* in_sizes, int n_in,
                              void* d_out, int out_size, void* d_ws, size_t ws_size,
                              hipStream_t stream) {
    const int*   stored  = (const int*)d_in[0];   // [N_store, 16] int32
    const int*   queries = (const int*)d_in[1];   // [N_query, 16] int32
    const float* vals    = (const float*)d_in[2]; // [N_store] f32
    float*       out     = (float*)d_out;         // [N_query] f32
    float*       hist    = (float*)d_ws;          // 65536 f32 bins

    int n_store = in_sizes[0] / REL_W;
    int n_query = in_sizes[1] / REL_W;

    // zero the histogram (d_ws is poisoned 0xAA and not re-poisoned between
    // replays, so we must re-zero every call — deterministic anyway)
    hipMemsetAsync(d_ws, 0, NBINS * sizeof(float), stream);

    const int BLK = 256;
    build_hist_kernel<<<(n_store + BLK - 1) / BLK, BLK, 0, stream>>>(stored, vals, hist, n_store);
    gather_kernel<<<(n_query + BLK - 1) / BLK, BLK, 0, stream>>>(queries, hist, out, n_query);
}